// Round 11
// baseline (738.425 us; speedup 1.0000x reference)
//
#include <hip/hip_runtime.h>
#include <hip/hip_bf16.h>
#include <hip/hip_fp16.h>

#define TT 24
#define FF 16
#define HH 64
#define GG 192   // 3*HH
#define WL_DW (GG*32)   // whh LDS dwords (rows of 32, XOR-swizzled)
#define M2_DW (GG*20)   // m2 LDS dwords (rows stride 20: 8 m1 + 1 bias + 11 pad/zero)

typedef __attribute__((ext_vector_type(4))) float f32x4;
typedef __attribute__((ext_vector_type(8))) _Float16 f16x8;

__device__ __forceinline__ float fast_rcp(float x){ return __builtin_amdgcn_rcpf(x); }
__device__ __forceinline__ float sigmoid_f(float x){
  return fast_rcp(1.0f + __expf(-x));
}
__device__ __forceinline__ float tanh_f(float x){
  float e = __expf(-2.0f * fabsf(x));
  float th = (1.0f - e) * fast_rcp(1.0f + e);
  return copysignf(th, x);
}
__device__ __forceinline__ float4 h4tof4(uint2 u){
  __half2 p0 = *(__half2*)&u.x, p1 = *(__half2*)&u.y;
  float2 f0 = __half22float2(p0), f1 = __half22float2(p1);
  return make_float4(f0.x, f0.y, f1.x, f1.y);
}
__device__ __forceinline__ uint pack_h2(float a, float b){
  ushort ha = __half_as_ushort(__float2half(a));
  ushort hb = __half_as_ushort(__float2half(b));
  return (uint)ha | ((uint)hb << 16);
}

// ---------------- CSR build ----------------
__global__ void k_deg(const int* __restrict__ ei, int E, int* __restrict__ deg){
  int i = blockIdx.x*blockDim.x + threadIdx.x;
  if(i<E) atomicAdd(&deg[ei[E+i]], 1);   // dst = ei[E+i]
}

__global__ __launch_bounds__(1024) void k_scan(const int* __restrict__ deg, int* __restrict__ offsets,
                                               float* __restrict__ dinv, int N){
  __shared__ int s[1024];
  int tid = threadIdx.x;
  int CH = (N + 1023) >> 10;
  int lo = tid*CH, hi = min(N, lo+CH);
  int sum=0;
  for(int j=lo;j<hi;j++){
    int d = deg[j];
    dinv[j] = rsqrtf((float)d + 1.0f);
    sum += d;
  }
  s[tid]=sum; __syncthreads();
  for(int o=1;o<1024;o<<=1){
    int v = 0;
    if(tid>=o) v = s[tid-o];
    __syncthreads();
    s[tid] += v;
    __syncthreads();
  }
  int run = s[tid]-sum;
  for(int j=lo;j<hi;j++){ offsets[j]=run; run += deg[j]; }
  if(tid==1023) offsets[N]=s[1023];
}

__global__ void k_fill(const int* __restrict__ ei, int E, const float* __restrict__ dinv,
                       const int* __restrict__ offsets, int* __restrict__ counters,
                       int2* __restrict__ csr2){
  int i = blockIdx.x*blockDim.x + threadIdx.x;
  if(i>=E) return;
  int s = ei[i], d = ei[E+i];
  int slot = offsets[d] + atomicAdd(&counters[d], 1);
  csr2[slot] = make_int2(s, __float_as_int(dinv[s]*dinv[d]));
}

// ---------------- weight prep: M1 = gcn_w @ w_ih^T (f16), c1, w_hh (f16) ----------------
__global__ void k_prep(const float* __restrict__ gcn_w, const float* __restrict__ gcn_b,
                       const float* __restrict__ w_ih, const float* __restrict__ b_ih,
                       const float* __restrict__ w_hh,
                       ushort* __restrict__ m1F, float* __restrict__ c1,
                       ushort* __restrict__ whhF){
  int tid = blockIdx.x*blockDim.x + threadIdx.x;
  if(tid < GG*FF){
    int j = tid >> 4, f = tid & 15;
    float s = 0.f;
    for(int k=0;k<HH;k++) s += gcn_w[f*HH+k]*w_ih[j*HH+k];
    m1F[tid] = __half_as_ushort(__float2half(s));
  } else if (tid < GG*FF + GG){
    int j = tid - GG*FF;
    float s = b_ih[j];
    for(int k=0;k<HH;k++) s += gcn_b[k]*w_ih[j*HH+k];
    c1[j] = s;
  }
  if(tid < GG*HH){
    whhF[tid] = __half_as_ushort(__float2half(w_hh[tid]));
  }
}

// ---------------- transpose+convert: x[t][n][f] fp32 -> xTh[n][t*16+f] fp16 ----------------
__global__ __launch_bounds__(256)
void k_xt2(const float* __restrict__ x, ushort* __restrict__ xTh, int N){
  __shared__ ushort tile[16][392];
  const int nbase = blockIdx.x * 16;
  const int tid = threadIdx.x;
  const int nd = tid >> 4, f = tid & 15;
  const int n = nbase + nd;
  for(int t=0; t<TT; t++){
    float v = (n < N) ? x[((size_t)t*N + n)*FF + f] : 0.f;
    tile[nd][t*16 + f] = __half_as_ushort(__float2half(v));
  }
  __syncthreads();
  uint* xo = (uint*)xTh;
  for(int i = tid; i < 16*192; i += 256){
    int d = i / 192, pos = i - d*192;
    int nn = nbase + d;
    if(nn < N) xo[(size_t)nn*192 + pos] = *(uint*)&tile[d][pos*2];
  }
}

// ---------------- aggregation: wave per dst node, fp16 rows, all 24 t at once ----------------
__global__ __launch_bounds__(256)
void k_aggTh(const ushort* __restrict__ xTh, const int* __restrict__ offsets,
             const int2* __restrict__ csr2, const float* __restrict__ dinv,
             ushort* __restrict__ aggF, int N){
  int wid = (blockIdx.x*blockDim.x + threadIdx.x) >> 6;
  if(wid >= N) return;
  const int l = threadIdx.x & 63;
  const int half = l >> 5, lh = l & 31;
  const int n = wid;

  float4 a0 = make_float4(0.f,0.f,0.f,0.f);
  float4 a1 = make_float4(0.f,0.f,0.f,0.f);
  float4 a2 = make_float4(0.f,0.f,0.f,0.f);

  const int lo = offsets[n], hi = offsets[n+1];
  for(int j = lo; j < hi; j += 4){
    int ja = j + half;
    int jb = j + 2 + half;
    bool okA = ja < hi, okB = jb < hi;
    int2 cA = csr2[okA ? ja : lo];
    int2 cB = csr2[okB ? jb : lo];
    float wA = okA ? __int_as_float(cA.y) : 0.f;
    float wB = okB ? __int_as_float(cB.y) : 0.f;
    const uint2* rA = (const uint2*)(xTh + (size_t)cA.x*384) + lh;
    const uint2* rB = (const uint2*)(xTh + (size_t)cB.x*384) + lh;
    uint2 uA0 = rA[0], uA1 = rA[32], uA2 = rA[64];
    uint2 uB0 = rB[0], uB1 = rB[32], uB2 = rB[64];
    float4 vA0 = h4tof4(uA0), vA1 = h4tof4(uA1), vA2 = h4tof4(uA2);
    float4 vB0 = h4tof4(uB0), vB1 = h4tof4(uB1), vB2 = h4tof4(uB2);
    a0.x += wA*vA0.x; a0.y += wA*vA0.y; a0.z += wA*vA0.z; a0.w += wA*vA0.w;
    a1.x += wA*vA1.x; a1.y += wA*vA1.y; a1.z += wA*vA1.z; a1.w += wA*vA1.w;
    a2.x += wA*vA2.x; a2.y += wA*vA2.y; a2.z += wA*vA2.z; a2.w += wA*vA2.w;
    a0.x += wB*vB0.x; a0.y += wB*vB0.y; a0.z += wB*vB0.z; a0.w += wB*vB0.w;
    a1.x += wB*vB1.x; a1.y += wB*vB1.y; a1.z += wB*vB1.z; a1.w += wB*vB1.w;
    a2.x += wB*vB2.x; a2.y += wB*vB2.y; a2.z += wB*vB2.z; a2.w += wB*vB2.w;
  }
  a0.x += __shfl_xor(a0.x, 32, 64); a0.y += __shfl_xor(a0.y, 32, 64);
  a0.z += __shfl_xor(a0.z, 32, 64); a0.w += __shfl_xor(a0.w, 32, 64);
  a1.x += __shfl_xor(a1.x, 32, 64); a1.y += __shfl_xor(a1.y, 32, 64);
  a1.z += __shfl_xor(a1.z, 32, 64); a1.w += __shfl_xor(a1.w, 32, 64);
  a2.x += __shfl_xor(a2.x, 32, 64); a2.y += __shfl_xor(a2.y, 32, 64);
  a2.z += __shfl_xor(a2.z, 32, 64); a2.w += __shfl_xor(a2.w, 32, 64);

  if(half == 0){
    float sn = dinv[n]; sn *= sn;
    const uint2* rS = (const uint2*)(xTh + (size_t)n*384) + lh;
    float4 s0 = h4tof4(rS[0]), s1 = h4tof4(rS[32]), s2 = h4tof4(rS[64]);
    a0.x += sn*s0.x; a0.y += sn*s0.y; a0.z += sn*s0.z; a0.w += sn*s0.w;
    a1.x += sn*s1.x; a1.y += sn*s1.y; a1.z += sn*s1.z; a1.w += sn*s1.w;
    a2.x += sn*s2.x; a2.y += sn*s2.y; a2.z += sn*s2.z; a2.w += sn*s2.w;
    float4 acc[3] = {a0, a1, a2};
    #pragma unroll
    for(int k=0;k<3;k++){
      int u  = lh + k*32;
      int t  = u >> 2, f4 = u & 3;
      size_t o = ((size_t)t*N + n)*FF + f4*4;
      float4 a = acc[k];
      ushort4 h;
      h.x = __half_as_ushort(__float2half(a.x));
      h.y = __half_as_ushort(__float2half(a.y));
      h.z = __half_as_ushort(__float2half(a.z));
      h.w = __half_as_ushort(__float2half(a.w));
      *(ushort4*)(aggF + o) = h;
    }
  }
}

// ---------------- barrier-free persistent GRU v3: weights in LDS ----------------
// 1 wave = 16 nodes x 64 ch (swapped MFMA: D[ch][node] = A(W) x B(h)).
// Weights staged once into block LDS (identical for all waves) -> VGPR ~100, no spill.
// h round-trips through wave-private swizzled LDS; input bias rides m2[k=16] x cAg[k=16]=1.
__global__ __launch_bounds__(256, 3)
void k_gru_all(const ushort* __restrict__ aggF,
               const ushort* __restrict__ whhF, const ushort* __restrict__ m1F,
               const float* __restrict__ c1, const float* __restrict__ bhh,
               const float* __restrict__ lin_w, const float* __restrict__ lin_b,
               float* __restrict__ out, int N, int P){
  __shared__ __align__(16) uint wl[WL_DW];   // 24 KB
  __shared__ __align__(16) uint ml[M2_DW];   // 15 KB
  __shared__ __align__(16) uint hw[4][512];  // 8 KB: per-wave 16 nodes x 32 dw
  __shared__ float bnl[64];                  // bhn
  const int tid = threadIdx.x;
  const int l = tid & 63, w = tid >> 6;
  const int nd = l & 15, g = l >> 4;
  const int wid = blockIdx.x*4 + w;
  const int node = wid*16 + nd;
  const int nodec = min(node, N-1);
  uint* myh = hw[w];

  // ---- cooperative weight staging ----
  const uint* whhU = (const uint*)whhF;
  for(int i=tid; i<WL_DW; i+=256){
    int r = i >> 5, d = i & 31;
    wl[(r<<5) + (d ^ ((r&7)<<2))] = whhU[i];
  }
  const uint* m1U = (const uint*)m1F;
  for(int i=tid; i<M2_DW; i+=256){
    int r = i / 20, d = i - r*20;
    uint v = 0u;
    if(d < 8) v = m1U[r*8 + d];
    else if(d == 8){
      float b = c1[r] + (r < 2*HH ? bhh[r] : 0.f);
      v = (uint)__half_as_ushort(__float2half(b));
    }
    ml[i] = v;
  }
  if(tid < 64) bnl[tid] = bhh[2*HH + tid];
  for(int i=l; i<512; i+=64) myh[i]=0u;   // zero own-wave h
  __syncthreads();   // the ONLY barrier

  float hreg[16];
  #pragma unroll
  for(int i=0;i<16;i++) hreg[i]=0.f;

  const f16x8 zf = (f16x8){0,0,0,0,0,0,0,0};
  f16x8 acst = zf;
  if(g==2) acst[0] = (_Float16)1.0f;   // k=16 slot -> bias lane
  f16x8 cAg = acst;
  if(g < 2) cAg = *(const f16x8*)(aggF + (size_t)nodec*FF + g*8);

  const int swz = (nd & 7) << 2;   // row&7 == nd&7 for both h rows and weight rows

  for(int t=0; t<TT; t++){
    // h B-frags from wave-private LDS
    f16x8 hB0 = *(const f16x8*)(myh + nd*32 + ((g*4)      ^ swz));
    f16x8 hB1 = *(const f16x8*)(myh + nd*32 + ((16 + g*4) ^ swz));

    // prefetch agg for t+1
    f16x8 pAg = cAg;
    if(g < 2 && t+1 < TT)
      pAg = *(const f16x8*)(aggF + (size_t)(t+1)*N*FF + (size_t)nodec*FF + g*8);

    #pragma unroll
    for(int c=0;c<4;c++){
      const int rr =        c*16 + nd;
      const int rz =  HH  + c*16 + nd;
      const int rn = 2*HH + c*16 + nd;
      f16x8 ar0 = *(const f16x8*)(wl + (rr<<5) + ((g*4)    ^ swz));
      f16x8 ar1 = *(const f16x8*)(wl + (rr<<5) + ((16+g*4) ^ swz));
      f16x8 az0 = *(const f16x8*)(wl + (rz<<5) + ((g*4)    ^ swz));
      f16x8 az1 = *(const f16x8*)(wl + (rz<<5) + ((16+g*4) ^ swz));
      f16x8 an0 = *(const f16x8*)(wl + (rn<<5) + ((g*4)    ^ swz));
      f16x8 an1 = *(const f16x8*)(wl + (rn<<5) + ((16+g*4) ^ swz));
      f16x8 mr  = *(const f16x8*)(ml + rr*20 + g*4);
      f16x8 mz  = *(const f16x8*)(ml + rz*20 + g*4);
      f16x8 mn  = *(const f16x8*)(ml + rn*20 + g*4);

      f32x4 R  = {0.f,0.f,0.f,0.f};
      f32x4 Z  = {0.f,0.f,0.f,0.f};
      f32x4 Nh = {0.f,0.f,0.f,0.f};
      f32x4 Ni = {0.f,0.f,0.f,0.f};
      R  = __builtin_amdgcn_mfma_f32_16x16x32_f16(ar0, hB0, R , 0,0,0);
      R  = __builtin_amdgcn_mfma_f32_16x16x32_f16(ar1, hB1, R , 0,0,0);
      R  = __builtin_amdgcn_mfma_f32_16x16x32_f16(mr,  cAg, R , 0,0,0);
      Z  = __builtin_amdgcn_mfma_f32_16x16x32_f16(az0, hB0, Z , 0,0,0);
      Z  = __builtin_amdgcn_mfma_f32_16x16x32_f16(az1, hB1, Z , 0,0,0);
      Z  = __builtin_amdgcn_mfma_f32_16x16x32_f16(mz,  cAg, Z , 0,0,0);
      Nh = __builtin_amdgcn_mfma_f32_16x16x32_f16(an0, hB0, Nh, 0,0,0);
      Nh = __builtin_amdgcn_mfma_f32_16x16x32_f16(an1, hB1, Nh, 0,0,0);
      Ni = __builtin_amdgcn_mfma_f32_16x16x32_f16(mn,  cAg, Ni, 0,0,0);

      float4 bb = *(const float4*)&bnl[c*16 + g*4];   // broadcast read
      const float bbv[4] = {bb.x, bb.y, bb.z, bb.w};
      #pragma unroll
      for(int i=0;i<4;i++){
        float r_ = sigmoid_f(R[i]);
        float z_ = sigmoid_f(Z[i]);
        float nn = tanh_f(Ni[i] + r_*(Nh[i] + bbv[i]));
        float hp = hreg[c*4+i];
        float hv = nn + z_*(hp - nn);
        hreg[c*4+i] = hv;
      }
      uint p0 = pack_h2(hreg[c*4+0], hreg[c*4+1]);
      uint p1 = pack_h2(hreg[c*4+2], hreg[c*4+3]);
      int dwb = c*8 + g*2;
      myh[nd*32 + ((dwb+0) ^ swz)] = p0;
      myh[nd*32 + ((dwb+1) ^ swz)] = p1;
    }
    cAg = pAg;
  }

  // ---- fused linear head: per-lane partial dot over its 16 ch, reduce over g ----
  for(int p=0; p<P; p++){
    float acc = 0.f;
    #pragma unroll
    for(int c=0;c<4;c++){
      float4 lw4 = *(const float4*)(lin_w + p*HH + c*16 + g*4);
      acc += lw4.x*hreg[c*4+0] + lw4.y*hreg[c*4+1]
           + lw4.z*hreg[c*4+2] + lw4.w*hreg[c*4+3];
    }
    acc += __shfl_xor(acc, 16, 64);
    acc += __shfl_xor(acc, 32, 64);
    if(g == 0 && node < N) out[(size_t)p*N + node] = acc + lin_b[p];
  }
}

extern "C" void kernel_launch(void* const* d_in, const int* in_sizes, int n_in,
                              void* d_out, int out_size, void* d_ws, size_t ws_size,
                              hipStream_t stream){
  const float* x     = (const float*)d_in[0];
  const float* gcn_w = (const float*)d_in[2];
  const float* gcn_b = (const float*)d_in[3];
  const float* w_ih  = (const float*)d_in[4];
  const float* w_hh  = (const float*)d_in[5];
  const float* b_ih  = (const float*)d_in[6];
  const float* b_hh  = (const float*)d_in[7];
  const float* lin_w = (const float*)d_in[8];
  const float* lin_b = (const float*)d_in[9];
  const int*   ei    = (const int*)d_in[10];
  const int E = in_sizes[10]/2;
  const int N = in_sizes[0]/(TT*FF);
  const int P = in_sizes[9];

  char* wsp = (char*)d_ws;
  auto alloc = [&](size_t bytes)->void*{ void* p = wsp; wsp += (bytes + 255) & ~(size_t)255; return p; };
  int*    deg      = (int*)   alloc((size_t)2*N*4);   // deg | counters adjacent -> one memset
  int*    counters = deg + N;
  int*    offsets  = (int*)   alloc((size_t)(N+1)*4);
  float*  dinv     = (float*) alloc((size_t)N*4);
  int2*   csr2     = (int2*)  alloc((size_t)E*8);
  ushort* xTh      = (ushort*)alloc((size_t)N*384*2);
  ushort* aggF     = (ushort*)alloc((size_t)TT*N*FF*2);
  ushort* m1F      = (ushort*)alloc((size_t)GG*FF*2);
  float*  c1       = (float*) alloc((size_t)GG*4);
  ushort* whhF     = (ushort*)alloc((size_t)GG*HH*2);

  hipMemsetAsync(deg, 0, (size_t)2*N*4, stream);

  k_deg  <<<(E+255)/256, 256, 0, stream>>>(ei, E, deg);
  k_scan <<<1, 1024, 0, stream>>>(deg, offsets, dinv, N);
  k_fill <<<(E+255)/256, 256, 0, stream>>>(ei, E, dinv, offsets, counters, csr2);
  k_prep <<<(GG*HH+255)/256, 256, 0, stream>>>(gcn_w, gcn_b, w_ih, b_ih, w_hh,
                                               m1F, c1, whhF);
  k_xt2  <<<(N+15)/16, 256, 0, stream>>>(x, xTh, N);
  k_aggTh<<<(N+3)/4, 256, 0, stream>>>(xTh, offsets, csr2, dinv, aggF, N);
  k_gru_all<<<(N+63)/64, 256, 0, stream>>>(aggF, whhF, m1F, c1, b_hh,
                                           lin_w, lin_b, (float*)d_out, N, P);
}

// Round 12
// 578.766 us; speedup vs baseline: 1.2759x; 1.2759x over previous
//
#include <hip/hip_runtime.h>
#include <hip/hip_bf16.h>
#include <hip/hip_fp16.h>

#define TT 24
#define FF 16
#define HH 64
#define GG 192   // 3*HH

typedef __attribute__((ext_vector_type(4))) float f32x4;
typedef __attribute__((ext_vector_type(8))) _Float16 f16x8;

#define PIN(v) asm volatile("" : "+v"(v))

__device__ __forceinline__ float fast_rcp(float x){ return __builtin_amdgcn_rcpf(x); }
__device__ __forceinline__ float sigmoid_f(float x){
  return fast_rcp(1.0f + __expf(-x));
}
__device__ __forceinline__ float tanh_f(float x){
  float e = __expf(-2.0f * fabsf(x));
  float th = (1.0f - e) * fast_rcp(1.0f + e);
  return copysignf(th, x);
}
__device__ __forceinline__ float4 h4tof4(uint2 u){
  __half2 p0 = *(__half2*)&u.x, p1 = *(__half2*)&u.y;
  float2 f0 = __half22float2(p0), f1 = __half22float2(p1);
  return make_float4(f0.x, f0.y, f1.x, f1.y);
}
__device__ __forceinline__ uint pack_h2(float a, float b){
  ushort ha = __half_as_ushort(__float2half(a));
  ushort hb = __half_as_ushort(__float2half(b));
  return (uint)ha | ((uint)hb << 16);
}

// ---------------- CSR build ----------------
__global__ void k_deg(const int* __restrict__ ei, int E, int* __restrict__ deg){
  int i = blockIdx.x*blockDim.x + threadIdx.x;
  if(i<E) atomicAdd(&deg[ei[E+i]], 1);   // dst = ei[E+i]
}

__global__ __launch_bounds__(1024) void k_scan(const int* __restrict__ deg, int* __restrict__ offsets,
                                               float* __restrict__ dinv, int N){
  __shared__ int s[1024];
  int tid = threadIdx.x;
  int CH = (N + 1023) >> 10;
  int lo = tid*CH, hi = min(N, lo+CH);
  int sum=0;
  for(int j=lo;j<hi;j++){
    int d = deg[j];
    dinv[j] = rsqrtf((float)d + 1.0f);
    sum += d;
  }
  s[tid]=sum; __syncthreads();
  for(int o=1;o<1024;o<<=1){
    int v = 0;
    if(tid>=o) v = s[tid-o];
    __syncthreads();
    s[tid] += v;
    __syncthreads();
  }
  int run = s[tid]-sum;
  for(int j=lo;j<hi;j++){ offsets[j]=run; run += deg[j]; }
  if(tid==1023) offsets[N]=s[1023];
}

__global__ void k_fill(const int* __restrict__ ei, int E, const float* __restrict__ dinv,
                       const int* __restrict__ offsets, int* __restrict__ counters,
                       int2* __restrict__ csr2){
  int i = blockIdx.x*blockDim.x + threadIdx.x;
  if(i>=E) return;
  int s = ei[i], d = ei[E+i];
  int slot = offsets[d] + atomicAdd(&counters[d], 1);
  csr2[slot] = make_int2(s, __float_as_int(dinv[s]*dinv[d]));
}

// ---------------- weight prep: M1 = gcn_w @ w_ih^T (f16), c1, w_hh (f16) ----------------
__global__ void k_prep(const float* __restrict__ gcn_w, const float* __restrict__ gcn_b,
                       const float* __restrict__ w_ih, const float* __restrict__ b_ih,
                       const float* __restrict__ w_hh,
                       ushort* __restrict__ m1F, float* __restrict__ c1,
                       ushort* __restrict__ whhF){
  int tid = blockIdx.x*blockDim.x + threadIdx.x;
  if(tid < GG*FF){
    int j = tid >> 4, f = tid & 15;
    float s = 0.f;
    for(int k=0;k<HH;k++) s += gcn_w[f*HH+k]*w_ih[j*HH+k];
    m1F[tid] = __half_as_ushort(__float2half(s));
  } else if (tid < GG*FF + GG){
    int j = tid - GG*FF;
    float s = b_ih[j];
    for(int k=0;k<HH;k++) s += gcn_b[k]*w_ih[j*HH+k];
    c1[j] = s;
  }
  if(tid < GG*HH){
    whhF[tid] = __half_as_ushort(__float2half(w_hh[tid]));
  }
}

// ---------------- transpose+convert: x[t][n][f] fp32 -> xTh[n][t*16+f] fp16 ----------------
__global__ __launch_bounds__(256)
void k_xt2(const float* __restrict__ x, ushort* __restrict__ xTh, int N){
  __shared__ ushort tile[16][392];
  const int nbase = blockIdx.x * 16;
  const int tid = threadIdx.x;
  const int nd = tid >> 4, f = tid & 15;
  const int n = nbase + nd;
  for(int t=0; t<TT; t++){
    float v = (n < N) ? x[((size_t)t*N + n)*FF + f] : 0.f;
    tile[nd][t*16 + f] = __half_as_ushort(__float2half(v));
  }
  __syncthreads();
  uint* xo = (uint*)xTh;
  for(int i = tid; i < 16*192; i += 256){
    int d = i / 192, pos = i - d*192;
    int nn = nbase + d;
    if(nn < N) xo[(size_t)nn*192 + pos] = *(uint*)&tile[d][pos*2];
  }
}

// ---------------- aggregation: wave per dst node, fp16 rows, all 24 t at once ----------------
__global__ __launch_bounds__(256)
void k_aggTh(const ushort* __restrict__ xTh, const int* __restrict__ offsets,
             const int2* __restrict__ csr2, const float* __restrict__ dinv,
             ushort* __restrict__ aggF, int N){
  int wid = (blockIdx.x*blockDim.x + threadIdx.x) >> 6;
  if(wid >= N) return;
  const int l = threadIdx.x & 63;
  const int half = l >> 5, lh = l & 31;
  const int n = wid;

  float4 a0 = make_float4(0.f,0.f,0.f,0.f);
  float4 a1 = make_float4(0.f,0.f,0.f,0.f);
  float4 a2 = make_float4(0.f,0.f,0.f,0.f);

  const int lo = offsets[n], hi = offsets[n+1];
  for(int j = lo; j < hi; j += 4){
    int ja = j + half;
    int jb = j + 2 + half;
    bool okA = ja < hi, okB = jb < hi;
    int2 cA = csr2[okA ? ja : lo];
    int2 cB = csr2[okB ? jb : lo];
    float wA = okA ? __int_as_float(cA.y) : 0.f;
    float wB = okB ? __int_as_float(cB.y) : 0.f;
    const uint2* rA = (const uint2*)(xTh + (size_t)cA.x*384) + lh;
    const uint2* rB = (const uint2*)(xTh + (size_t)cB.x*384) + lh;
    uint2 uA0 = rA[0], uA1 = rA[32], uA2 = rA[64];
    uint2 uB0 = rB[0], uB1 = rB[32], uB2 = rB[64];
    float4 vA0 = h4tof4(uA0), vA1 = h4tof4(uA1), vA2 = h4tof4(uA2);
    float4 vB0 = h4tof4(uB0), vB1 = h4tof4(uB1), vB2 = h4tof4(uB2);
    a0.x += wA*vA0.x; a0.y += wA*vA0.y; a0.z += wA*vA0.z; a0.w += wA*vA0.w;
    a1.x += wA*vA1.x; a1.y += wA*vA1.y; a1.z += wA*vA1.z; a1.w += wA*vA1.w;
    a2.x += wA*vA2.x; a2.y += wA*vA2.y; a2.z += wA*vA2.z; a2.w += wA*vA2.w;
    a0.x += wB*vB0.x; a0.y += wB*vB0.y; a0.z += wB*vB0.z; a0.w += wB*vB0.w;
    a1.x += wB*vB1.x; a1.y += wB*vB1.y; a1.z += wB*vB1.z; a1.w += wB*vB1.w;
    a2.x += wB*vB2.x; a2.y += wB*vB2.y; a2.z += wB*vB2.z; a2.w += wB*vB2.w;
  }
  a0.x += __shfl_xor(a0.x, 32, 64); a0.y += __shfl_xor(a0.y, 32, 64);
  a0.z += __shfl_xor(a0.z, 32, 64); a0.w += __shfl_xor(a0.w, 32, 64);
  a1.x += __shfl_xor(a1.x, 32, 64); a1.y += __shfl_xor(a1.y, 32, 64);
  a1.z += __shfl_xor(a1.z, 32, 64); a1.w += __shfl_xor(a1.w, 32, 64);
  a2.x += __shfl_xor(a2.x, 32, 64); a2.y += __shfl_xor(a2.y, 32, 64);
  a2.z += __shfl_xor(a2.z, 32, 64); a2.w += __shfl_xor(a2.w, 32, 64);

  if(half == 0){
    float sn = dinv[n]; sn *= sn;
    const uint2* rS = (const uint2*)(xTh + (size_t)n*384) + lh;
    float4 s0 = h4tof4(rS[0]), s1 = h4tof4(rS[32]), s2 = h4tof4(rS[64]);
    a0.x += sn*s0.x; a0.y += sn*s0.y; a0.z += sn*s0.z; a0.w += sn*s0.w;
    a1.x += sn*s1.x; a1.y += sn*s1.y; a1.z += sn*s1.z; a1.w += sn*s1.w;
    a2.x += sn*s2.x; a2.y += sn*s2.y; a2.z += sn*s2.z; a2.w += sn*s2.w;
    float4 acc[3] = {a0, a1, a2};
    #pragma unroll
    for(int k=0;k<3;k++){
      int u  = lh + k*32;
      int t  = u >> 2, f4 = u & 3;
      size_t o = ((size_t)t*N + n)*FF + f4*4;
      float4 a = acc[k];
      ushort4 h;
      h.x = __half_as_ushort(__float2half(a.x));
      h.y = __half_as_ushort(__float2half(a.y));
      h.z = __half_as_ushort(__float2half(a.z));
      h.w = __half_as_ushort(__float2half(a.w));
      *(ushort4*)(aggF + o) = h;
    }
  }
}

// ---------------- barrier-free persistent GRU: pinned register weights ----------------
// 1 wave = 16 nodes x 64 ch (swapped MFMA: D[ch][node] = A(W) x B(h)).
// All 36 weight fragments loaded ONCE and pinned via opaque asm (+v) so the compiler
// cannot rematerialize the loads inside the t-loop (R9/R10 showed VGPR=64..84 => reloads).
__global__ __launch_bounds__(256, 2)
void k_gru_all(const ushort* __restrict__ aggF,
               const ushort* __restrict__ whhF, const ushort* __restrict__ m1F,
               const float* __restrict__ c1, const float* __restrict__ bhh,
               const float* __restrict__ lin_w, const float* __restrict__ lin_b,
               float* __restrict__ out, int N, int P){
  __shared__ __align__(16) uint hw[4][512];   // per-wave 16 nodes x 32 dwords (64 f16)
  const int tid = threadIdx.x;
  const int l = tid & 63, w = tid >> 6;
  const int nd = l & 15, g = l >> 4;
  const int wid = blockIdx.x*4 + w;
  const int node = wid*16 + nd;
  const int nodec = min(node, N-1);
  uint* myh = hw[w];

  // ---- stationary weights (A-frags, rows = ch with ch_in_tile = nd), PINNED ----
  f32x4 wAr[4][2], wAz[4][2], wAn[4][2], mAr[4], mAz[4], mAn[4];
  const f16x8 zf = (f16x8){0,0,0,0,0,0,0,0};
  #pragma unroll
  for(int c=0;c<4;c++){
    const int chr =        c*16 + nd;
    const int chz =  HH  + c*16 + nd;
    const int chn = 2*HH + c*16 + nd;
    #pragma unroll
    for(int ks=0;ks<2;ks++){
      wAr[c][ks] = *(const f32x4*)(whhF + chr*HH + ks*32 + g*8);
      wAz[c][ks] = *(const f32x4*)(whhF + chz*HH + ks*32 + g*8);
      wAn[c][ks] = *(const f32x4*)(whhF + chn*HH + ks*32 + g*8);
      PIN(wAr[c][ks]); PIN(wAz[c][ks]); PIN(wAn[c][ks]);
    }
    f16x8 mr = zf, mz = zf, mn = zf;
    if(g < 2){
      mr = *(const f16x8*)(m1F + chr*FF + g*8);
      mz = *(const f16x8*)(m1F + chz*FF + g*8);
      mn = *(const f16x8*)(m1F + chn*FF + g*8);
    } else if(g == 2){
      mr[0] = (_Float16)(c1[chr] + bhh[chr]);
      mz[0] = (_Float16)(c1[chz] + bhh[chz]);
      mn[0] = (_Float16)(c1[chn]);
    }
    mAr[c] = __builtin_bit_cast(f32x4, mr);
    mAz[c] = __builtin_bit_cast(f32x4, mz);
    mAn[c] = __builtin_bit_cast(f32x4, mn);
    PIN(mAr[c]); PIN(mAz[c]); PIN(mAn[c]);
  }

  // bhn (hidden n-gate bias) per lane's 16 ch
  float4 bb[4];
  #pragma unroll
  for(int c=0;c<4;c++) bb[c] = *(const float4*)(bhh + 2*HH + c*16 + g*4);

  float hreg[16];
  #pragma unroll
  for(int i=0;i<16;i++) hreg[i]=0.f;

  // zero wave-private h (no barrier needed: same wave)
  for(int i=l;i<512;i+=64) myh[i]=0u;

  // agg B-frag: g<2 -> agg[node][g*8..]; g==2 -> k=16 slot = 1.0 (bias); g==3 -> 0
  f16x8 acst = zf;
  if(g==2) acst[0] = (_Float16)1.0f;
  f16x8 cAg = acst;
  if(g < 2) cAg = *(const f16x8*)(aggF + (size_t)nodec*FF + g*8);

  const int swz = (nd & 7) << 2;

  for(int t=0; t<TT; t++){
    // h B-frags from wave-private LDS (swizzled)
    f16x8 hB0, hB1;
    {
      int a0 = nd*32 + ((0*16 + g*4) ^ swz);
      int a1 = nd*32 + ((1*16 + g*4) ^ swz);
      hB0 = *(const f16x8*)(myh + a0);
      hB1 = *(const f16x8*)(myh + a1);
    }

    // prefetch agg for t+1
    f16x8 pAg = cAg;
    if(g < 2 && t+1 < TT)
      pAg = *(const f16x8*)(aggF + (size_t)(t+1)*N*FF + (size_t)nodec*FF + g*8);

    #pragma unroll
    for(int c=0;c<4;c++){
      f32x4 R  = {0.f,0.f,0.f,0.f};
      f32x4 Z  = {0.f,0.f,0.f,0.f};
      f32x4 Nh = {0.f,0.f,0.f,0.f};
      f32x4 Ni = {0.f,0.f,0.f,0.f};
      R  = __builtin_amdgcn_mfma_f32_16x16x32_f16(__builtin_bit_cast(f16x8, wAr[c][0]), hB0, R , 0,0,0);
      R  = __builtin_amdgcn_mfma_f32_16x16x32_f16(__builtin_bit_cast(f16x8, wAr[c][1]), hB1, R , 0,0,0);
      R  = __builtin_amdgcn_mfma_f32_16x16x32_f16(__builtin_bit_cast(f16x8, mAr[c]),    cAg, R , 0,0,0);
      Z  = __builtin_amdgcn_mfma_f32_16x16x32_f16(__builtin_bit_cast(f16x8, wAz[c][0]), hB0, Z , 0,0,0);
      Z  = __builtin_amdgcn_mfma_f32_16x16x32_f16(__builtin_bit_cast(f16x8, wAz[c][1]), hB1, Z , 0,0,0);
      Z  = __builtin_amdgcn_mfma_f32_16x16x32_f16(__builtin_bit_cast(f16x8, mAz[c]),    cAg, Z , 0,0,0);
      Nh = __builtin_amdgcn_mfma_f32_16x16x32_f16(__builtin_bit_cast(f16x8, wAn[c][0]), hB0, Nh, 0,0,0);
      Nh = __builtin_amdgcn_mfma_f32_16x16x32_f16(__builtin_bit_cast(f16x8, wAn[c][1]), hB1, Nh, 0,0,0);
      Ni = __builtin_amdgcn_mfma_f32_16x16x32_f16(__builtin_bit_cast(f16x8, mAn[c]),    cAg, Ni, 0,0,0);

      const float bbv[4] = {bb[c].x, bb[c].y, bb[c].z, bb[c].w};
      #pragma unroll
      for(int i=0;i<4;i++){
        float r_ = sigmoid_f(R[i]);
        float z_ = sigmoid_f(Z[i]);
        float nn = tanh_f(Ni[i] + r_*(Nh[i] + bbv[i]));
        float hp = hreg[c*4+i];
        float hv = nn + z_*(hp - nn);
        hreg[c*4+i] = hv;
      }
      uint p0 = pack_h2(hreg[c*4+0], hreg[c*4+1]);
      uint p1 = pack_h2(hreg[c*4+2], hreg[c*4+3]);
      int dwb = c*8 + g*2;
      myh[nd*32 + ((dwb+0) ^ swz)] = p0;
      myh[nd*32 + ((dwb+1) ^ swz)] = p1;
    }
    cAg = pAg;
  }

  // ---- fused linear head: per-lane partial dot over its 16 ch, reduce over g ----
  for(int p=0; p<P; p++){
    float acc = 0.f;
    #pragma unroll
    for(int c=0;c<4;c++){
      float4 lw4 = *(const float4*)(lin_w + p*HH + c*16 + g*4);
      acc += lw4.x*hreg[c*4+0] + lw4.y*hreg[c*4+1]
           + lw4.z*hreg[c*4+2] + lw4.w*hreg[c*4+3];
    }
    acc += __shfl_xor(acc, 16, 64);
    acc += __shfl_xor(acc, 32, 64);
    if(g == 0 && node < N) out[(size_t)p*N + node] = acc + lin_b[p];
  }
}

extern "C" void kernel_launch(void* const* d_in, const int* in_sizes, int n_in,
                              void* d_out, int out_size, void* d_ws, size_t ws_size,
                              hipStream_t stream){
  const float* x     = (const float*)d_in[0];
  const float* gcn_w = (const float*)d_in[2];
  const float* gcn_b = (const float*)d_in[3];
  const float* w_ih  = (const float*)d_in[4];
  const float* w_hh  = (const float*)d_in[5];
  const float* b_ih  = (const float*)d_in[6];
  const float* b_hh  = (const float*)d_in[7];
  const float* lin_w = (const float*)d_in[8];
  const float* lin_b = (const float*)d_in[9];
  const int*   ei    = (const int*)d_in[10];
  const int E = in_sizes[10]/2;
  const int N = in_sizes[0]/(TT*FF);
  const int P = in_sizes[9];

  char* wsp = (char*)d_ws;
  auto alloc = [&](size_t bytes)->void*{ void* p = wsp; wsp += (bytes + 255) & ~(size_t)255; return p; };
  int*    deg      = (int*)   alloc((size_t)2*N*4);   // deg | counters adjacent -> one memset
  int*    counters = deg + N;
  int*    offsets  = (int*)   alloc((size_t)(N+1)*4);
  float*  dinv     = (float*) alloc((size_t)N*4);
  int2*   csr2     = (int2*)  alloc((size_t)E*8);
  ushort* xTh      = (ushort*)alloc((size_t)N*384*2);
  ushort* aggF     = (ushort*)alloc((size_t)TT*N*FF*2);
  ushort* m1F      = (ushort*)alloc((size_t)GG*FF*2);
  float*  c1       = (float*) alloc((size_t)GG*4);
  ushort* whhF     = (ushort*)alloc((size_t)GG*HH*2);

  hipMemsetAsync(deg, 0, (size_t)2*N*4, stream);

  k_deg  <<<(E+255)/256, 256, 0, stream>>>(ei, E, deg);
  k_scan <<<1, 1024, 0, stream>>>(deg, offsets, dinv, N);
  k_fill <<<(E+255)/256, 256, 0, stream>>>(ei, E, dinv, offsets, counters, csr2);
  k_prep <<<(GG*HH+255)/256, 256, 0, stream>>>(gcn_w, gcn_b, w_ih, b_ih, w_hh,
                                               m1F, c1, whhF);
  k_xt2  <<<(N+15)/16, 256, 0, stream>>>(x, xTh, N);
  k_aggTh<<<(N+3)/4, 256, 0, stream>>>(xTh, offsets, csr2, dinv, aggF, N);
  k_gru_all<<<(N+63)/64, 256, 0, stream>>>(aggF, whhF, m1F, c1, b_hh,
                                           lin_w, lin_b, (float*)d_out, N, P);
}

// Round 13
// 547.125 us; speedup vs baseline: 1.3496x; 1.0578x over previous
//
#include <hip/hip_runtime.h>
#include <hip/hip_bf16.h>
#include <hip/hip_fp16.h>

#define TT 24
#define FF 16
#define HH 64
#define GG 192   // 3*HH

typedef __attribute__((ext_vector_type(4))) float f32x4;
typedef __attribute__((ext_vector_type(8))) _Float16 f16x8;

__device__ __forceinline__ float fast_rcp(float x){ return __builtin_amdgcn_rcpf(x); }
__device__ __forceinline__ float sigmoid_f(float x){
  return fast_rcp(1.0f + __expf(-x));
}
__device__ __forceinline__ float tanh_f(float x){
  float e = __expf(-2.0f * fabsf(x));
  float th = (1.0f - e) * fast_rcp(1.0f + e);
  return copysignf(th, x);
}
__device__ __forceinline__ float4 h4tof4(uint2 u){
  __half2 p0 = *(__half2*)&u.x, p1 = *(__half2*)&u.y;
  float2 f0 = __half22float2(p0), f1 = __half22float2(p1);
  return make_float4(f0.x, f0.y, f1.x, f1.y);
}
__device__ __forceinline__ uint pack_h2(float a, float b){
  ushort ha = __half_as_ushort(__float2half(a));
  ushort hb = __half_as_ushort(__float2half(b));
  return (uint)ha | ((uint)hb << 16);
}

// ---------------- fused prologue: xt2 || deg || prep (mutually independent) ----------------
__global__ __launch_bounds__(256)
void k_pre(const float* __restrict__ x, ushort* __restrict__ xTh,
           const int* __restrict__ ei, int E, int* __restrict__ deg,
           const float* __restrict__ gcn_w, const float* __restrict__ gcn_b,
           const float* __restrict__ w_ih, const float* __restrict__ b_ih,
           const float* __restrict__ w_hh,
           ushort* __restrict__ m1F, float* __restrict__ c1, ushort* __restrict__ whhF,
           int N, int GX, int GD){
  __shared__ ushort tile[16][392];
  const int bid = blockIdx.x;
  const int tid = threadIdx.x;
  if(bid < GX){
    // ---- transpose+convert x[t][n][f] fp32 -> xTh[n][t*16+f] fp16 ----
    const int nbase = bid * 16;
    const int nd = tid >> 4, f = tid & 15;
    const int n = nbase + nd;
    for(int t=0; t<TT; t++){
      float v = (n < N) ? x[((size_t)t*N + n)*FF + f] : 0.f;
      tile[nd][t*16 + f] = __half_as_ushort(__float2half(v));
    }
    __syncthreads();
    uint* xo = (uint*)xTh;
    for(int i = tid; i < 16*192; i += 256){
      int d = i / 192, pos = i - d*192;
      int nn = nbase + d;
      if(nn < N) xo[(size_t)nn*192 + pos] = *(uint*)&tile[d][pos*2];
    }
  } else if(bid < GX + GD){
    // ---- degree count ----
    int i = (bid - GX)*256 + tid;
    if(i < E) atomicAdd(&deg[ei[E+i]], 1);
  } else {
    // ---- weight prep ----
    int t2 = (bid - GX - GD)*256 + tid;
    if(t2 < GG*FF){
      int j = t2 >> 4, f = t2 & 15;
      float s = 0.f;
      for(int k=0;k<HH;k++) s += gcn_w[f*HH+k]*w_ih[j*HH+k];
      m1F[t2] = __half_as_ushort(__float2half(s));
    } else if (t2 < GG*FF + GG){
      int j = t2 - GG*FF;
      float s = b_ih[j];
      for(int k=0;k<HH;k++) s += gcn_b[k]*w_ih[j*HH+k];
      c1[j] = s;
    }
    if(t2 < GG*HH){
      whhF[t2] = __half_as_ushort(__float2half(w_hh[t2]));
    }
  }
}

// ---------------- scan: offsets + dinv ----------------
__global__ __launch_bounds__(1024) void k_scan(const int* __restrict__ deg, int* __restrict__ offsets,
                                               float* __restrict__ dinv, int N){
  __shared__ int s[1024];
  int tid = threadIdx.x;
  int CH = (N + 1023) >> 10;
  int lo = tid*CH, hi = min(N, lo+CH);
  int sum=0;
  for(int j=lo;j<hi;j++){
    int d = deg[j];
    dinv[j] = rsqrtf((float)d + 1.0f);
    sum += d;
  }
  s[tid]=sum; __syncthreads();
  for(int o=1;o<1024;o<<=1){
    int v = 0;
    if(tid>=o) v = s[tid-o];
    __syncthreads();
    s[tid] += v;
    __syncthreads();
  }
  int run = s[tid]-sum;
  for(int j=lo;j<hi;j++){ offsets[j]=run; run += deg[j]; }
  if(tid==1023) offsets[N]=s[1023];
}

__global__ void k_fill(const int* __restrict__ ei, int E, const float* __restrict__ dinv,
                       const int* __restrict__ offsets, int* __restrict__ counters,
                       int2* __restrict__ csr2){
  int i = blockIdx.x*blockDim.x + threadIdx.x;
  if(i>=E) return;
  int s = ei[i], d = ei[E+i];
  int slot = offsets[d] + atomicAdd(&counters[d], 1);
  csr2[slot] = make_int2(s, __float_as_int(dinv[s]*dinv[d]));
}

// ---------------- aggregation: wave per dst node, fp16 rows, all 24 t at once ----------------
__global__ __launch_bounds__(256)
void k_aggTh(const ushort* __restrict__ xTh, const int* __restrict__ offsets,
             const int2* __restrict__ csr2, const float* __restrict__ dinv,
             ushort* __restrict__ aggF, int N){
  int wid = (blockIdx.x*blockDim.x + threadIdx.x) >> 6;
  if(wid >= N) return;
  const int l = threadIdx.x & 63;
  const int half = l >> 5, lh = l & 31;
  const int n = wid;

  float4 a0 = make_float4(0.f,0.f,0.f,0.f);
  float4 a1 = make_float4(0.f,0.f,0.f,0.f);
  float4 a2 = make_float4(0.f,0.f,0.f,0.f);

  const int lo = offsets[n], hi = offsets[n+1];
  for(int j = lo; j < hi; j += 4){
    int ja = j + half;
    int jb = j + 2 + half;
    bool okA = ja < hi, okB = jb < hi;
    int2 cA = csr2[okA ? ja : lo];
    int2 cB = csr2[okB ? jb : lo];
    float wA = okA ? __int_as_float(cA.y) : 0.f;
    float wB = okB ? __int_as_float(cB.y) : 0.f;
    const uint2* rA = (const uint2*)(xTh + (size_t)cA.x*384) + lh;
    const uint2* rB = (const uint2*)(xTh + (size_t)cB.x*384) + lh;
    uint2 uA0 = rA[0], uA1 = rA[32], uA2 = rA[64];
    uint2 uB0 = rB[0], uB1 = rB[32], uB2 = rB[64];
    float4 vA0 = h4tof4(uA0), vA1 = h4tof4(uA1), vA2 = h4tof4(uA2);
    float4 vB0 = h4tof4(uB0), vB1 = h4tof4(uB1), vB2 = h4tof4(uB2);
    a0.x += wA*vA0.x; a0.y += wA*vA0.y; a0.z += wA*vA0.z; a0.w += wA*vA0.w;
    a1.x += wA*vA1.x; a1.y += wA*vA1.y; a1.z += wA*vA1.z; a1.w += wA*vA1.w;
    a2.x += wA*vA2.x; a2.y += wA*vA2.y; a2.z += wA*vA2.z; a2.w += wA*vA2.w;
    a0.x += wB*vB0.x; a0.y += wB*vB0.y; a0.z += wB*vB0.z; a0.w += wB*vB0.w;
    a1.x += wB*vB1.x; a1.y += wB*vB1.y; a1.z += wB*vB1.z; a1.w += wB*vB1.w;
    a2.x += wB*vB2.x; a2.y += wB*vB2.y; a2.z += wB*vB2.z; a2.w += wB*vB2.w;
  }
  a0.x += __shfl_xor(a0.x, 32, 64); a0.y += __shfl_xor(a0.y, 32, 64);
  a0.z += __shfl_xor(a0.z, 32, 64); a0.w += __shfl_xor(a0.w, 32, 64);
  a1.x += __shfl_xor(a1.x, 32, 64); a1.y += __shfl_xor(a1.y, 32, 64);
  a1.z += __shfl_xor(a1.z, 32, 64); a1.w += __shfl_xor(a1.w, 32, 64);
  a2.x += __shfl_xor(a2.x, 32, 64); a2.y += __shfl_xor(a2.y, 32, 64);
  a2.z += __shfl_xor(a2.z, 32, 64); a2.w += __shfl_xor(a2.w, 32, 64);

  if(half == 0){
    float sn = dinv[n]; sn *= sn;
    const uint2* rS = (const uint2*)(xTh + (size_t)n*384) + lh;
    float4 s0 = h4tof4(rS[0]), s1 = h4tof4(rS[32]), s2 = h4tof4(rS[64]);
    a0.x += sn*s0.x; a0.y += sn*s0.y; a0.z += sn*s0.z; a0.w += sn*s0.w;
    a1.x += sn*s1.x; a1.y += sn*s1.y; a1.z += sn*s1.z; a1.w += sn*s1.w;
    a2.x += sn*s2.x; a2.y += sn*s2.y; a2.z += sn*s2.z; a2.w += sn*s2.w;
    float4 acc[3] = {a0, a1, a2};
    #pragma unroll
    for(int k=0;k<3;k++){
      int u  = lh + k*32;
      int t  = u >> 2, f4 = u & 3;
      size_t o = ((size_t)t*N + n)*FF + f4*4;
      float4 a = acc[k];
      ushort4 h;
      h.x = __half_as_ushort(__float2half(a.x));
      h.y = __half_as_ushort(__float2half(a.y));
      h.z = __half_as_ushort(__float2half(a.z));
      h.w = __half_as_ushort(__float2half(a.w));
      *(ushort4*)(aggF + o) = h;
    }
  }
}

// ---------------- GRU v5: 16 nodes/block, 4 waves split over channels ----------------
// Wave w owns ch [16w,16w+16) for the block's 16 nodes. Per wave-t: 9 MFMA
// (D[ch][node] = A(W) x B(h)) + 4-cell epilogue. h (16 nodes x 64 ch, f16) in
// double-buffered XOR-swizzled LDS; ONE barrier per t. 12500 waves -> high TLP.
__global__ __launch_bounds__(256, 4)
void k_gru5(const ushort* __restrict__ aggF,
            const ushort* __restrict__ whhF, const ushort* __restrict__ m1F,
            const float* __restrict__ c1, const float* __restrict__ bhh,
            const float* __restrict__ lin_w, const float* __restrict__ lin_b,
            float* __restrict__ out, int N, int P){
  __shared__ __align__(16) uint hb[2][512];   // 2 x (16 nodes x 64 ch f16) = 4 KB
  const int tid = threadIdx.x;
  const int l = tid & 63, w = tid >> 6;
  const int nd = l & 15, g = l >> 4;
  const int node = blockIdx.x*16 + nd;
  const int nodec = min(node, N-1);
  const int chB = 16*w;

  // stationary weights for my ch tile (9 frags = 36 VGPR)
  const f16x8 zf = (f16x8){0,0,0,0,0,0,0,0};
  f16x8 ar0,ar1,az0,az1,an0,an1, mr,mz,mn;
  {
    const int rr =        chB + nd;
    const int rz =  HH  + chB + nd;
    const int rn = 2*HH + chB + nd;
    ar0 = *(const f16x8*)(whhF + rr*HH      + g*8);
    ar1 = *(const f16x8*)(whhF + rr*HH + 32 + g*8);
    az0 = *(const f16x8*)(whhF + rz*HH      + g*8);
    az1 = *(const f16x8*)(whhF + rz*HH + 32 + g*8);
    an0 = *(const f16x8*)(whhF + rn*HH      + g*8);
    an1 = *(const f16x8*)(whhF + rn*HH + 32 + g*8);
    mr = zf; mz = zf; mn = zf;
    if(g < 2){
      mr = *(const f16x8*)(m1F + rr*FF + g*8);
      mz = *(const f16x8*)(m1F + rz*FF + g*8);
      mn = *(const f16x8*)(m1F + rn*FF + g*8);
    } else if(g == 2){
      mr[0] = (_Float16)(c1[rr] + bhh[rr]);
      mz[0] = (_Float16)(c1[rz] + bhh[rz]);
      mn[0] = (_Float16)(c1[rn]);
    }
  }
  float4 bb = *(const float4*)(bhh + 2*HH + chB + g*4);

  float hreg[4] = {0.f,0.f,0.f,0.f};

  // zero h buffer 0
  for(int i=tid; i<512; i+=256) hb[0][i]=0u;

  // agg B-frag: col=node, k: g<2 -> agg features; g==2 -> k=16 slot carries bias x 1.0
  f16x8 cAg = zf;
  if(g==2) cAg[0] = (_Float16)1.0f;
  if(g < 2) cAg = *(const f16x8*)(aggF + (size_t)nodec*FF + g*8);

  const int swz = (nd & 7) << 2;
  __syncthreads();

  for(int t=0; t<TT; t++){
    const uint* cb = hb[t & 1];
    uint* nb = hb[(t & 1) ^ 1];

    f16x8 hB0 = *(const f16x8*)(cb + nd*32 + ((g*4)      ^ swz));
    f16x8 hB1 = *(const f16x8*)(cb + nd*32 + ((16 + g*4) ^ swz));

    f16x8 pAg = cAg;
    if(g < 2 && t+1 < TT)
      pAg = *(const f16x8*)(aggF + (size_t)(t+1)*N*FF + (size_t)nodec*FF + g*8);

    f32x4 R  = {0.f,0.f,0.f,0.f};
    f32x4 Z  = {0.f,0.f,0.f,0.f};
    f32x4 Nh = {0.f,0.f,0.f,0.f};
    f32x4 Ni = {0.f,0.f,0.f,0.f};
    R  = __builtin_amdgcn_mfma_f32_16x16x32_f16(ar0, hB0, R , 0,0,0);
    R  = __builtin_amdgcn_mfma_f32_16x16x32_f16(ar1, hB1, R , 0,0,0);
    R  = __builtin_amdgcn_mfma_f32_16x16x32_f16(mr,  cAg, R , 0,0,0);
    Z  = __builtin_amdgcn_mfma_f32_16x16x32_f16(az0, hB0, Z , 0,0,0);
    Z  = __builtin_amdgcn_mfma_f32_16x16x32_f16(az1, hB1, Z , 0,0,0);
    Z  = __builtin_amdgcn_mfma_f32_16x16x32_f16(mz,  cAg, Z , 0,0,0);
    Nh = __builtin_amdgcn_mfma_f32_16x16x32_f16(an0, hB0, Nh, 0,0,0);
    Nh = __builtin_amdgcn_mfma_f32_16x16x32_f16(an1, hB1, Nh, 0,0,0);
    Ni = __builtin_amdgcn_mfma_f32_16x16x32_f16(mn,  cAg, Ni, 0,0,0);

    const float bbv[4] = {bb.x, bb.y, bb.z, bb.w};
    #pragma unroll
    for(int i=0;i<4;i++){
      float r_ = sigmoid_f(R[i]);
      float z_ = sigmoid_f(Z[i]);
      float nn = tanh_f(Ni[i] + r_*(Nh[i] + bbv[i]));
      hreg[i] = nn + z_*(hreg[i] - nn);
    }
    uint2 pk;
    pk.x = pack_h2(hreg[0], hreg[1]);
    pk.y = pack_h2(hreg[2], hreg[3]);
    *(uint2*)(nb + nd*32 + ((8*w + 2*g) ^ swz)) = pk;

    cAg = pAg;
    __syncthreads();
  }

  // ---- fused linear head ----
  float* hs = (float*)hb;   // 16 nodes x 64 ch fp32 = 4 KB (reuse)
  #pragma unroll
  for(int i=0;i<4;i++) hs[nd*64 + chB + g*4 + i] = hreg[i];
  __syncthreads();
  if(tid < 16*P){
    int ndl = tid & 15, p = tid >> 4;
    int node2 = blockIdx.x*16 + ndl;
    if(node2 < N){
      float acc = lin_b[p];
      const float* hrow = hs + ndl*64;
      #pragma unroll
      for(int q=0;q<16;q++){
        float4 v = *(const float4*)(hrow + q*4);
        float4 lw = *(const float4*)(lin_w + p*HH + q*4);
        acc += v.x*lw.x + v.y*lw.y + v.z*lw.z + v.w*lw.w;
      }
      out[(size_t)p*N + node2] = acc;
    }
  }
}

extern "C" void kernel_launch(void* const* d_in, const int* in_sizes, int n_in,
                              void* d_out, int out_size, void* d_ws, size_t ws_size,
                              hipStream_t stream){
  const float* x     = (const float*)d_in[0];
  const float* gcn_w = (const float*)d_in[2];
  const float* gcn_b = (const float*)d_in[3];
  const float* w_ih  = (const float*)d_in[4];
  const float* w_hh  = (const float*)d_in[5];
  const float* b_ih  = (const float*)d_in[6];
  const float* b_hh  = (const float*)d_in[7];
  const float* lin_w = (const float*)d_in[8];
  const float* lin_b = (const float*)d_in[9];
  const int*   ei    = (const int*)d_in[10];
  const int E = in_sizes[10]/2;
  const int N = in_sizes[0]/(TT*FF);
  const int P = in_sizes[9];

  char* wsp = (char*)d_ws;
  auto alloc = [&](size_t bytes)->void*{ void* p = wsp; wsp += (bytes + 255) & ~(size_t)255; return p; };
  int*    deg      = (int*)   alloc((size_t)2*N*4);   // deg | counters -> one memset
  int*    counters = deg + N;
  int*    offsets  = (int*)   alloc((size_t)(N+1)*4);
  float*  dinv     = (float*) alloc((size_t)N*4);
  int2*   csr2     = (int2*)  alloc((size_t)E*8);
  ushort* xTh      = (ushort*)alloc((size_t)N*384*2);
  ushort* aggF     = (ushort*)alloc((size_t)TT*N*FF*2);
  ushort* m1F      = (ushort*)alloc((size_t)GG*FF*2);
  float*  c1       = (float*) alloc((size_t)GG*4);
  ushort* whhF     = (ushort*)alloc((size_t)GG*HH*2);

  hipMemsetAsync(deg, 0, (size_t)2*N*4, stream);

  const int GX = (N + 15)/16;
  const int GD = (E + 255)/256;
  const int GP = (GG*HH + 255)/256;
  k_pre  <<<GX + GD + GP, 256, 0, stream>>>(x, xTh, ei, E, deg,
                                            gcn_w, gcn_b, w_ih, b_ih, w_hh,
                                            m1F, c1, whhF, N, GX, GD);
  k_scan <<<1, 1024, 0, stream>>>(deg, offsets, dinv, N);
  k_fill <<<(E+255)/256, 256, 0, stream>>>(ei, E, dinv, offsets, counters, csr2);
  k_aggTh<<<(N+3)/4, 256, 0, stream>>>(xTh, offsets, csr2, dinv, aggF, N);
  k_gru5 <<<(N+15)/16, 256, 0, stream>>>(aggF, whhF, m1F, c1, b_hh,
                                         lin_w, lin_b, (float*)d_out, N, P);
}